// Round 6
// baseline (184.739 us; speedup 1.0000x reference)
//
#include <hip/hip_runtime.h>

typedef __bf16 bf16x8 __attribute__((ext_vector_type(8)));
typedef __bf16 bf16x4 __attribute__((ext_vector_type(4)));
typedef float  f32x4  __attribute__((ext_vector_type(4)));
typedef float  f32x16 __attribute__((ext_vector_type(16)));
typedef unsigned int u32;

#define MFMA_BF16(a, b, c) __builtin_amdgcn_mfma_f32_16x16x32_bf16((a), (b), (c), 0, 0, 0)
#define MFMA32(a, b, c) __builtin_amdgcn_mfma_f32_32x32x16_bf16((a), (b), (c), 0, 0, 0)
#define NEG_INF (-1e30f)
// softmax scale folded with log2(e): exp(s*0.125) == exp2(s*0.125*1.442695)
#define SCL 0.18033688f

__device__ __forceinline__ void gld16(const void* g, void* l) {
  __builtin_amdgcn_global_load_lds(
      (const __attribute__((address_space(1))) void*)g,
      (__attribute__((address_space(3))) void*)l, 16, 0, 0);
}

// ---------------------------------------------------------------------------
// Cast fp32 -> bf16, 8 elems/thread.
// ---------------------------------------------------------------------------
__global__ void cast_f32_bf16(const float* __restrict__ in,
                              __bf16* __restrict__ out, int n) {
  int i = (blockIdx.x * 256 + threadIdx.x) * 8;
  if (i >= n) return;
  float4 a = *(const float4*)&in[i];
  float4 b = *(const float4*)&in[i + 4];
  bf16x8 v;
  v[0] = (__bf16)a.x; v[1] = (__bf16)a.y; v[2] = (__bf16)a.z; v[3] = (__bf16)a.w;
  v[4] = (__bf16)b.x; v[5] = (__bf16)b.y; v[6] = (__bf16)b.z; v[7] = (__bf16)b.w;
  *(bf16x8*)&out[i] = v;
}

// ---------------------------------------------------------------------------
// Transpose: in [R][C] fp32 -> out [C][R] bf16. 32x32 tiles, 256 threads.
// ---------------------------------------------------------------------------
__global__ void transpose_f32_bf16(const float* __restrict__ in,
                                   __bf16* __restrict__ out, int R, int C) {
  __shared__ float t[32][33];
  int tx = threadIdx.x & 31, ty = threadIdx.x >> 5;  // 32 x 8
  int x = blockIdx.x * 32 + tx;
  int y0 = blockIdx.y * 32 + ty;
#pragma unroll
  for (int i = 0; i < 4; ++i)
    t[ty + 8 * i][tx] = in[(size_t)(y0 + 8 * i) * C + x];
  __syncthreads();
  int x2 = blockIdx.y * 32 + tx;
#pragma unroll
  for (int i = 0; i < 4; ++i)
    out[(size_t)(blockIdx.x * 32 + ty + 8 * i) * R + x2] = (__bf16)t[tx][ty + 8 * i];
}

// ---------------------------------------------------------------------------
// GEMM: C[M][N] = A[M][K]*Bt[N][K]^T + bias[N]. A,Bt bf16, fp32 accum.
// m97 structure + XOR-swizzled LDS (source-permuted gld16; conflict-free).
// Still used for the proj GEMM.
// ---------------------------------------------------------------------------
#define BN 128
#define BK 64

template <int BMT, typename TC>
__global__ __launch_bounds__(256) void gemm_bt_bias(
    const __bf16* __restrict__ A, const __bf16* __restrict__ Bt,
    const float* __restrict__ bias, TC* __restrict__ Cmat,
    int M, int N, int K) {
  constexpr int NI = BMT / 32;  // A chunks per thread; MFMA row-tiles per wave
  __shared__ __align__(16) __bf16 As[BMT * BK];
  __shared__ __align__(16) __bf16 Bs[BN * BK];
  int tid = threadIdx.x;
  int wave = tid >> 6, lane = tid & 63;
  int l16 = lane & 15, quad = lane >> 4;
  int wm = wave >> 1, wn = wave & 1;
  int m0 = blockIdx.y * BMT, n0 = blockIdx.x * BN;

  f32x4 acc[NI][4];
#pragma unroll
  for (int i = 0; i < NI; ++i)
#pragma unroll
    for (int j = 0; j < 4; ++j) acc[i][j] = (f32x4){0.f, 0.f, 0.f, 0.f};

  int row = tid >> 3;                                // 0..31 (+32*i)
  // swizzled source column: slot (tid&7) of row r fetches chunk (tid&7)^(r&7)
  int kc = ((tid & 7) ^ ((tid >> 3) & 7)) * 8;       // i*32 doesn't change r&7
  // fragment-read xor key (elements): chunk cc -> slot cc^(l16&7)
  int xr = (l16 & 7) * 8;

  for (int k0 = 0; k0 < K; k0 += BK) {
#pragma unroll
    for (int i = 0; i < NI; ++i)
      gld16(&A[(size_t)(m0 + row + i * 32) * K + k0 + kc],
            (char*)As + (i * 256 + wave * 64) * 16);
#pragma unroll
    for (int j = 0; j < 4; ++j)
      gld16(&Bt[(size_t)(n0 + row + j * 32) * K + k0 + kc],
            (char*)Bs + (j * 256 + wave * 64) * 16);
    __syncthreads();
#pragma unroll
    for (int ks = 0; ks < 2; ++ks) {
      bf16x8 af[NI], bfr[4];
#pragma unroll
      for (int i = 0; i < NI; ++i)
        af[i] = *(const bf16x8*)&As[(wm * (BMT / 2) + i * 16 + l16) * BK +
                                    ((ks * 32 + quad * 8) ^ xr)];
#pragma unroll
      for (int j = 0; j < 4; ++j)
        bfr[j] = *(const bf16x8*)&Bs[(wn * 64 + j * 16 + l16) * BK +
                                     ((ks * 32 + quad * 8) ^ xr)];
#pragma unroll
      for (int i = 0; i < NI; ++i)
#pragma unroll
        for (int j = 0; j < 4; ++j) acc[i][j] = MFMA_BF16(af[i], bfr[j], acc[i][j]);
    }
    __syncthreads();
  }
  // epilogue: D row = quad*4+r, col = lane&15 within each 16x16 tile
#pragma unroll
  for (int i = 0; i < NI; ++i) {
#pragma unroll
    for (int j = 0; j < 4; ++j) {
      int col = n0 + wn * 64 + j * 16 + l16;
      float bv = bias[col];
#pragma unroll
      for (int r = 0; r < 4; ++r) {
        int rw = m0 + wm * (BMT / 2) + i * 16 + quad * 4 + r;
        Cmat[(size_t)rw * N + col] = (TC)(acc[i][j][r] + bv);
      }
    }
  }
}

// ---------------------------------------------------------------------------
// 8-phase qkv GEMM: C[4096][3072] = A[4096][1024] * Bt[3072][1024]^T + bias.
// 256x192 tile, 512 threads (8 waves, 2M x 4N), BK=64 as two K=32 halves.
// Grid 16x16 = 256 blocks = exactly 1 block/CU. (See round-0/1 notes.)
// Epilogue fuses the V transpose: cols >= 2048 go to vt[bh*64+d][t] directly.
// ---------------------------------------------------------------------------
#define BARX do { asm volatile("" ::: "memory"); __builtin_amdgcn_s_barrier(); \
                  asm volatile("" ::: "memory"); } while (0)
#define WLGKM do { asm volatile("s_waitcnt lgkmcnt(0)" ::: "memory"); \
                   __builtin_amdgcn_sched_barrier(0); } while (0)
#define WVM4 asm volatile("s_waitcnt vmcnt(4)" ::: "memory")
#define STA8(SBUF, SKS, T) do { \
    gld16(srcA1 + (size_t)(T) * 64 + (SKS) * 32, (char*)&As[SBUF][SKS][0] + tid * 16); \
    gld16(srcA2 + (size_t)(T) * 64 + (SKS) * 32, (char*)&As[SBUF][SKS][0] + tid * 16 + 8192); \
  } while (0)
#define STB8(SBUF, SKS, T) do { \
    gld16(srcB1 + (size_t)(T) * 64 + (SKS) * 32, (char*)&Bs[SBUF][SKS][0] + tid * 16); \
    gld16(srcB2 + (size_t)(T) * 64 + (SKS) * 32, (char*)&Bs[SBUF][SKS][0] + tid * 16 + 8192); \
  } while (0)
#define LDA4(CBUF, CKS, MQ) do { \
    const __bf16* p_ = &As[CBUF][CKS][(wm * 128 + (MQ) * 64 + l16) * 32 + xrd]; \
    af[0] = *(const bf16x8*)(p_);        af[1] = *(const bf16x8*)(p_ + 512); \
    af[2] = *(const bf16x8*)(p_ + 1024); af[3] = *(const bf16x8*)(p_ + 1536); \
  } while (0)
#define LDB3(CBUF, CKS) do { \
    const __bf16* p_ = &Bs[CBUF][CKS][(wn * 48 + l16) * 32 + xrd]; \
    bfr[0] = *(const bf16x8*)(p_);       bfr[1] = *(const bf16x8*)(p_ + 512); \
    bfr[2] = *(const bf16x8*)(p_ + 1024); \
  } while (0)
#define MM12(MQ) do { \
    __builtin_amdgcn_s_setprio(1); \
    _Pragma("unroll") for (int mi_ = 0; mi_ < 4; ++mi_) \
    _Pragma("unroll") for (int nj_ = 0; nj_ < 3; ++nj_) \
      acc[(MQ) * 4 + mi_][nj_] = MFMA_BF16(af[mi_], bfr[nj_], acc[(MQ) * 4 + mi_][nj_]); \
    __builtin_amdgcn_s_setprio(0); \
  } while (0)

__global__ __launch_bounds__(512, 2) void gemm_qkv_8ph(
    const __bf16* __restrict__ A, const __bf16* __restrict__ Bt,
    const float* __restrict__ bias, __bf16* __restrict__ qkv,
    __bf16* __restrict__ vt) {
  constexpr int GK = 1024, GN = 3072, NT = 16;  // K, N, K-tiles
  // [buf][khalf][row*32+col]; 16 KiB per region, 128 KiB total.
  __shared__ __align__(16) __bf16 As[2][2][256 * 32];
  __shared__ __align__(16) __bf16 Bs[2][2][256 * 32];  // rows 192..255 = pad
  const int tid = threadIdx.x;
  const int wave = tid >> 6, lane = tid & 63;
  const int l16 = lane & 15, quad = lane >> 4;
  const int wm = wave >> 2, wn = wave & 3;
  const int m0 = blockIdx.y * 256, n0 = blockIdx.x * 192;

  // staging: thread -> (row=tid>>2, slot=tid&3); source chunk = slot^((row>>1)&3)
  const int row0 = tid >> 2;                       // 0..127 (+128 on call 2)
  const int kc = (((tid & 3) ^ ((row0 >> 1) & 3)) * 8);
  // fragment-read xor key: chunk = quad ^ ((row>>1)&3); row>>1 dep reduces to l16
  const int xrd = (quad ^ ((l16 >> 1) & 3)) * 8;

  const __bf16* srcA1 = A + (size_t)(m0 + row0) * GK + kc;
  const __bf16* srcA2 = srcA1 + (size_t)128 * GK;
  const __bf16* srcB1 = Bt + (size_t)(n0 + row0) * GK + kc;
  const int br2 = (row0 + 128 < 192) ? row0 + 128 : 191;  // clamp pad rows
  const __bf16* srcB2 = Bt + (size_t)(n0 + br2) * GK + kc;

  f32x4 acc[8][3];
#pragma unroll
  for (int m = 0; m < 8; ++m)
#pragma unroll
    for (int n = 0; n < 3; ++n) acc[m][n] = (f32x4){0.f, 0.f, 0.f, 0.f};

  // prologue: tile0 (both halves) + tile1 ks0; wait tile0, keep t1ks0 in flight
  STA8(0, 0, 0); STB8(0, 0, 0);
  STA8(0, 1, 0); STB8(0, 1, 0);
  STA8(1, 0, 1); STB8(1, 0, 1);
  WVM4;
  BARX;

  bf16x8 af[4], bfr[3];
#pragma unroll 1
  for (int i = 0; i < NT / 2; ++i) {
    const int v = 2 * i + 1;
    const int t2 = (2 * i + 2 < NT) ? 2 * i + 2 : NT - 1;  // clamped: junk
    const int t3 = (2 * i + 3 < NT) ? 2 * i + 3 : NT - 1;  // staged, never read
    // ph1: compute (buf0, ks0, Mquad0)
    LDA4(0, 0, 0); LDB3(0, 0); STA8(1, 1, v);
    BARX; WLGKM; MM12(0); BARX;
    // ph2: (buf0, ks0, Mquad1); B frags reused
    LDA4(0, 0, 1); STB8(1, 1, v);
    BARX; WLGKM; MM12(1); BARX;
    // ph3: (buf0, ks1, Mquad0); buf0.ks0 free after ph2 -> restage
    LDA4(0, 1, 0); LDB3(0, 1); STA8(0, 0, t2);
    BARX; WLGKM; MM12(0); BARX;
    // ph4: (buf0, ks1, Mquad1); counted wait: tile v fully landed, 2 halves in flight
    LDA4(0, 1, 1); STB8(0, 0, t2);
    BARX; WLGKM; MM12(1); WVM4; BARX;
    // ph5: (buf1, ks0, Mquad0); buf0.ks1 free after ph4 -> restage
    LDA4(1, 0, 0); LDB3(1, 0); STA8(0, 1, t2);
    BARX; WLGKM; MM12(0); BARX;
    // ph6
    LDA4(1, 0, 1); STB8(0, 1, t2);
    BARX; WLGKM; MM12(1); BARX;
    // ph7: (buf1, ks1, Mquad0); buf1.ks0 free after ph6 -> restage
    LDA4(1, 1, 0); LDB3(1, 1); STA8(1, 0, t3);
    BARX; WLGKM; MM12(0); BARX;
    // ph8; counted wait: tile 2i+2 fully landed for next iteration's ph1
    LDA4(1, 1, 1); STB8(1, 0, t3);
    BARX; WLGKM; MM12(1); WVM4; BARX;
  }

  // epilogue: D row = quad*4+r (M), col = l16 (N). V cols write vt directly.
#pragma unroll
  for (int n = 0; n < 3; ++n) {
    const int c0 = n0 + wn * 48 + n * 16;  // wave-uniform; 2048 is 16-aligned
    const int col = c0 + l16;
    const float bv = bias[col];
    if (c0 < 2048) {
#pragma unroll
      for (int m = 0; m < 8; ++m) {
        const int rw = m0 + wm * 128 + m * 16 + quad * 4;
#pragma unroll
        for (int r = 0; r < 4; ++r)
          qkv[(size_t)(rw + r) * GN + col] = (__bf16)(acc[m][n][r] + bv);
      }
    } else {
      const int h = (col - 2048) >> 6, d = col & 63;
#pragma unroll
      for (int m = 0; m < 8; ++m) {
        const int t0 = m0 + wm * 128 + m * 16 + quad * 4;
        const int b = t0 >> 11, tt = t0 & 2047;
        bf16x4 pb;
#pragma unroll
        for (int r = 0; r < 4; ++r) pb[r] = (__bf16)(acc[m][n][r] + bv);
        *(bf16x4*)&vt[(size_t)((b * 16 + h) * 64 + d) * 2048 + tt] = pb;
      }
    }
  }
}

// ---------------------------------------------------------------------------
// Causal flash attention, 32x32 MFMA, in-register P (no Ps LDS).
// Round 6: round-5 failed (absmax 1.98) -- root-caused to the
// v_permlane32_swap_b32 DIRECTION. True semantics (the only one consistent
// with the verified HK/m214v22 recipe, where vdst = the EARLY cvt_pk pair and
// both results feed consecutive B-frag words): vdst.row1 <-> vsrc.row0, i.e.
//   new vdst = {lanes<32: old vdst lo, lanes>=32: old vsrc lo}
//   new vsrc = {lanes<32: old vdst hi, lanes>=32: old vsrc hi}
// So call SWAP32(vdst=early_pair a, vsrc=late_pair b):
//   a' per lane-pair = (lo: own a, hi: partner's b)  == B-frag word w0
//   b'               = (lo: partner's a, hi: own b)  == B-frag word w2
// Round-5's call had vdst/vsrc reversed -> every PV key scrambled. All other
// mappings re-audited: k-permutation assumptions cancel between A and B
// operands; C/D layout is m74/m101-verified. Everything else unchanged:
//   - 32x32x16 MFMA halves LDS bytes/FLOP (round-4 was LDS-issue-bound)
//   - S^T formulation, P packed in-register (no Ps LDS)
//   - LDS 32 KB dbuf K/V; 128-thr blocks (2 waves); grid (32 bh, 32 qt)
// ---------------------------------------------------------------------------
#define CVTPK(D, LO, HI) \
  asm("v_cvt_pk_bf16_f32 %0, %1, %2" : "=v"(D) : "v"(LO), "v"(HI))
#define SWAP32(DST, SRC) \
  asm("v_permlane32_swap_b32 %0, %1" : "+v"(DST), "+v"(SRC))

__device__ __forceinline__ bf16x8 mk8(u32 a, u32 b, u32 c, u32 d) {
  union { u32 u[4]; bf16x8 h; } x;
  x.u[0] = a; x.u[1] = b; x.u[2] = c; x.u[3] = d;
  return x.h;
}

__global__ __launch_bounds__(128, 3) void attn_causal(
    const __bf16* __restrict__ qkv, const __bf16* __restrict__ vt,
    __bf16* __restrict__ y) {
  __shared__ __align__(16) __bf16 Kb[2][64 * 64];  // [key][dimchunk^(key&7)]
  __shared__ __align__(16) __bf16 Vb[2][64 * 64];  // [dim][keychunk^(dim&7)]
  const int tid = threadIdx.x;
  const int wave = tid >> 6, lane = tid & 63;
  const int l32 = lane & 31, hi = lane >> 5;
  const int bh = blockIdx.x;
  const int b = bh >> 4, h = bh & 15;
  const int RS = 3072;
  const int qt = 31 - (int)blockIdx.y;             // big blocks first

  // staging: 128 threads, 4 chunks each per operand; slot=tid&7 of row r
  // holds source chunk (tid&7)^(r&7); r&7 == (tid>>3)&7 for all i (i*16%8==0)
  const int row8 = tid >> 3;                       // 0..15 (+16*i)
  const int kcs = ((tid & 7) ^ (row8 & 7)) * 8;    // source-permuted col
  const __bf16* kbase = qkv + (size_t)(b * 2048) * RS + 1024 + h * 64 + kcs;
  const __bf16* vbase = vt + (size_t)(bh * 64) * 2048 + kcs;

  // Q fragments (B-operand): col=q=l32, k=hi*8+e -> row-major b128 loads
  const __bf16* qp = qkv + (size_t)(b * 2048 + qt * 64 + wave * 32 + l32) * RS +
                     h * 64 + hi * 8;
  bf16x8 qf[4];
#pragma unroll
  for (int kc = 0; kc < 4; ++kc) qf[kc] = *(const bf16x8*)(qp + kc * 16);

  float l4[4] = {0.f, 0.f, 0.f, 0.f};
  f32x16 o0, o1;
#pragma unroll
  for (int r = 0; r < 16; ++r) { o0[r] = 0.f; o1[r] = 0.f; }

  // stage tile 0 into buffer 0
#pragma unroll
  for (int i = 0; i < 4; ++i) {
    gld16(kbase + (size_t)(i * 16 + row8) * RS, (char*)Kb[0] + (i * 128 + tid) * 16);
    gld16(vbase + (size_t)(i * 16 + row8) * 2048, (char*)Vb[0] + (i * 128 + tid) * 16);
  }
  __syncthreads();

  const int xr7 = l32 & 7;
  for (int kt = 0; kt <= qt; ++kt) {
    const int cur = kt & 1;
    if (kt < qt) {
#pragma unroll
      for (int i = 0; i < 4; ++i) {
        gld16(kbase + (size_t)((kt + 1) * 64 + i * 16 + row8) * RS,
              (char*)Kb[cur ^ 1] + (i * 128 + tid) * 16);
        gld16(vbase + (size_t)(i * 16 + row8) * 2048 + (kt + 1) * 64,
              (char*)Vb[cur ^ 1] + (i * 128 + tid) * 16);
      }
    }

    // S^T = K Q^T : c[kb][r] = S^T[key=kb*32+(r&3)+8*(r>>2)+4*hi][q=l32]
    f32x16 c0, c1;
#pragma unroll
    for (int r = 0; r < 16; ++r) { c0[r] = 0.f; c1[r] = 0.f; }
    __builtin_amdgcn_s_setprio(1);
#pragma unroll
    for (int kc = 0; kc < 4; ++kc) {
      const int sw = ((kc * 2 + hi) ^ xr7) << 3;
      bf16x8 kf0 = *(const bf16x8*)&Kb[cur][l32 * 64 + sw];
      bf16x8 kf1 = *(const bf16x8*)&Kb[cur][(32 + l32) * 64 + sw];
      c0 = MFMA32(kf0, qf[kc], c0);
      c1 = MFMA32(kf1, qf[kc], c1);
    }
    __builtin_amdgcn_s_setprio(0);

    // causal mask only on the diagonal tile (uniform branch)
    if (kt == qt) {
      const int qloc = wave * 32 + l32;
#pragma unroll
      for (int r = 0; r < 16; ++r) {
        const int kl = (r & 3) + 8 * (r >> 2) + 4 * hi;
        if (kl > qloc) c0[r] = NEG_INF;
        if (32 + kl > qloc) c1[r] = NEG_INF;
      }
    }

    // softmax + in-register pack to PV B-frags pb[kc] (keys kc*16+hi*8+e).
    // Pairing: a0=keys(4hi+0,1), a1=(4hi+2,3), b0=(8+4hi+0,1), b1=(8+4hi+2,3).
    // SWAP32(a,b) [vdst=a]: a'=(lo: own a, hi: partner b) = w0/w1;
    //                       b'=(lo: partner a, hi: own b) = w2/w3.
    bf16x8 pb[4];
#pragma unroll
    for (int kb = 0; kb < 2; ++kb) {
      float pv[16];
#pragma unroll
      for (int r = 0; r < 16; ++r) {
        const float sv = (kb ? c1[r] : c0[r]);
        pv[r] = __builtin_amdgcn_exp2f(sv * SCL);
        l4[r & 3] += pv[r];
      }
      u32 a0, a1, b0, b1;
      CVTPK(a0, pv[0], pv[1]);   CVTPK(a1, pv[2], pv[3]);
      CVTPK(b0, pv[4], pv[5]);   CVTPK(b1, pv[6], pv[7]);
      SWAP32(a0, b0); SWAP32(a1, b1);
      pb[kb * 2 + 0] = mk8(a0, a1, b0, b1);
      CVTPK(a0, pv[8], pv[9]);   CVTPK(a1, pv[10], pv[11]);
      CVTPK(b0, pv[12], pv[13]); CVTPK(b1, pv[14], pv[15]);
      SWAP32(a0, b0); SWAP32(a1, b1);
      pb[kb * 2 + 1] = mk8(a0, a1, b0, b1);
    }

    // O^T += V^T P : o[db][r] = O^T[d=db*32+(r&3)+8*(r>>2)+4*hi][q=l32]
    __builtin_amdgcn_s_setprio(1);
#pragma unroll
    for (int kc = 0; kc < 4; ++kc) {
      const int sw = ((kc * 2 + hi) ^ xr7) << 3;
      bf16x8 vf0 = *(const bf16x8*)&Vb[cur][l32 * 64 + sw];
      bf16x8 vf1 = *(const bf16x8*)&Vb[cur][(32 + l32) * 64 + sw];
      o0 = MFMA32(vf0, pb[kc], o0);
      o1 = MFMA32(vf1, pb[kc], o1);
    }
    __builtin_amdgcn_s_setprio(0);
    __syncthreads();  // drains DMA; next tile ready
  }

  // l: lane owns 32 of the 64 keys per tile; partner (lane^32) owns the rest
  float lred = (l4[0] + l4[1]) + (l4[2] + l4[3]);
  lred += __shfl_xor(lred, 32);
  const float inv = 1.f / lred;

  // store: lane's q = qt*64+wave*32+l32; d = db*32 + g*8 + hi*4 + (r&3)
  const int orow = b * 2048 + qt * 64 + wave * 32 + l32;
  __bf16* yb = y + (size_t)orow * 1024 + h * 64 + hi * 4;
#pragma unroll
  for (int db = 0; db < 2; ++db) {
#pragma unroll
    for (int g = 0; g < 4; ++g) {
      bf16x4 w;
#pragma unroll
      for (int j = 0; j < 4; ++j)
        w[j] = (__bf16)((db ? o1[g * 4 + j] : o0[g * 4 + j]) * inv);
      *(bf16x4*)&yb[db * 32 + g * 8] = w;
    }
  }
}

// ---------------------------------------------------------------------------
extern "C" void kernel_launch(void* const* d_in, const int* in_sizes, int n_in,
                              void* d_out, int out_size, void* d_ws, size_t ws_size,
                              hipStream_t stream) {
  (void)in_sizes; (void)n_in; (void)out_size; (void)ws_size;
  const float* x      = (const float*)d_in[0];  // [2,2048,1024] fp32
  const float* w_attn = (const float*)d_in[1];  // [1024,3072]
  const float* b_attn = (const float*)d_in[2];  // [3072]
  const float* w_proj = (const float*)d_in[3];  // [1024,1024]
  const float* b_proj = (const float*)d_in[4];  // [1024]
  float* out = (float*)d_out;                   // [2,2048,1024] fp32

  __bf16* wt_attn = (__bf16*)d_ws;                       // [3072][1024]
  __bf16* wt_proj = wt_attn + (size_t)3072 * 1024;       // [1024][1024]
  __bf16* qkv     = wt_proj + (size_t)1024 * 1024;       // [4096][3072]
  __bf16* ybuf    = qkv + (size_t)4096 * 3072;           // [4096][1024]
  __bf16* vtbuf   = ybuf + (size_t)4096 * 1024;          // [32*64][2048]

  // x -> bf16, staged in ybuf (attention overwrites it later; same stream)
  cast_f32_bf16<<<4096 * 1024 / 2048, 256, 0, stream>>>(x, ybuf, 4096 * 1024);

  transpose_f32_bf16<<<dim3(3072 / 32, 1024 / 32), 256, 0, stream>>>(w_attn, wt_attn, 1024, 3072);
  transpose_f32_bf16<<<dim3(1024 / 32, 1024 / 32), 256, 0, stream>>>(w_proj, wt_proj, 1024, 1024);

  // qkv = x @ w_attn + b_attn; V columns written transposed into vtbuf
  // (8-phase 256x192 tile; grid 16x16 = 256 blocks = 1/CU)
  gemm_qkv_8ph<<<dim3(3072 / 192, 4096 / 256), 512, 0, stream>>>(
      ybuf, wt_attn, b_attn, qkv, vtbuf);

  // y = causal_attention(qkv, vt), overwrites ybuf
  // (1024 blocks of 128 threads, 32x32 MFMA, ~4-5 blocks/CU)
  attn_causal<<<dim3(32, 32), 128, 0, stream>>>(qkv, vtbuf, ybuf);

  // out = y @ w_proj + b_proj   (512 blocks, BM=64 for occupancy)
  gemm_bt_bias<64, float><<<dim3(1024 / BN, 4096 / 64), 256, 0, stream>>>(
      ybuf, wt_proj, b_proj, out, 4096, 1024, 1024);
}

// Round 7
// 174.823 us; speedup vs baseline: 1.0567x; 1.0567x over previous
//
#include <hip/hip_runtime.h>

typedef __bf16 bf16x8 __attribute__((ext_vector_type(8)));
typedef __bf16 bf16x4 __attribute__((ext_vector_type(4)));
typedef float  f32x4  __attribute__((ext_vector_type(4)));
typedef float  f32x16 __attribute__((ext_vector_type(16)));
typedef unsigned int u32;

#define MFMA_BF16(a, b, c) __builtin_amdgcn_mfma_f32_16x16x32_bf16((a), (b), (c), 0, 0, 0)
#define MFMA32(a, b, c) __builtin_amdgcn_mfma_f32_32x32x16_bf16((a), (b), (c), 0, 0, 0)
#define NEG_INF (-1e30f)
// softmax scale folded with log2(e): exp(s*0.125) == exp2(s*0.125*1.442695)
#define SCL 0.18033688f

__device__ __forceinline__ void gld16(const void* g, void* l) {
  __builtin_amdgcn_global_load_lds(
      (const __attribute__((address_space(1))) void*)g,
      (__attribute__((address_space(3))) void*)l, 16, 0, 0);
}

// ---------------------------------------------------------------------------
// Cast fp32 -> bf16, 8 elems/thread.
// ---------------------------------------------------------------------------
__global__ void cast_f32_bf16(const float* __restrict__ in,
                              __bf16* __restrict__ out, int n) {
  int i = (blockIdx.x * 256 + threadIdx.x) * 8;
  if (i >= n) return;
  float4 a = *(const float4*)&in[i];
  float4 b = *(const float4*)&in[i + 4];
  bf16x8 v;
  v[0] = (__bf16)a.x; v[1] = (__bf16)a.y; v[2] = (__bf16)a.z; v[3] = (__bf16)a.w;
  v[4] = (__bf16)b.x; v[5] = (__bf16)b.y; v[6] = (__bf16)b.z; v[7] = (__bf16)b.w;
  *(bf16x8*)&out[i] = v;
}

// ---------------------------------------------------------------------------
// Transpose: in [R][C] fp32 -> out [C][R] bf16. 32x32 tiles, 256 threads.
// ---------------------------------------------------------------------------
__global__ void transpose_f32_bf16(const float* __restrict__ in,
                                   __bf16* __restrict__ out, int R, int C) {
  __shared__ float t[32][33];
  int tx = threadIdx.x & 31, ty = threadIdx.x >> 5;  // 32 x 8
  int x = blockIdx.x * 32 + tx;
  int y0 = blockIdx.y * 32 + ty;
#pragma unroll
  for (int i = 0; i < 4; ++i)
    t[ty + 8 * i][tx] = in[(size_t)(y0 + 8 * i) * C + x];
  __syncthreads();
  int x2 = blockIdx.y * 32 + tx;
#pragma unroll
  for (int i = 0; i < 4; ++i)
    out[(size_t)(blockIdx.x * 32 + ty + 8 * i) * R + x2] = (__bf16)t[tx][ty + 8 * i];
}

// ---------------------------------------------------------------------------
// GEMM: C[M][N] = A[M][K]*Bt[N][K]^T + bias[N]. A,Bt bf16, fp32 accum.
// m97 structure + XOR-swizzled LDS (source-permuted gld16; conflict-free).
// Still used for the proj GEMM.
// ---------------------------------------------------------------------------
#define BN 128
#define BK 64

template <int BMT, typename TC>
__global__ __launch_bounds__(256) void gemm_bt_bias(
    const __bf16* __restrict__ A, const __bf16* __restrict__ Bt,
    const float* __restrict__ bias, TC* __restrict__ Cmat,
    int M, int N, int K) {
  constexpr int NI = BMT / 32;  // A chunks per thread; MFMA row-tiles per wave
  __shared__ __align__(16) __bf16 As[BMT * BK];
  __shared__ __align__(16) __bf16 Bs[BN * BK];
  int tid = threadIdx.x;
  int wave = tid >> 6, lane = tid & 63;
  int l16 = lane & 15, quad = lane >> 4;
  int wm = wave >> 1, wn = wave & 1;
  int m0 = blockIdx.y * BMT, n0 = blockIdx.x * BN;

  f32x4 acc[NI][4];
#pragma unroll
  for (int i = 0; i < NI; ++i)
#pragma unroll
    for (int j = 0; j < 4; ++j) acc[i][j] = (f32x4){0.f, 0.f, 0.f, 0.f};

  int row = tid >> 3;                                // 0..31 (+32*i)
  // swizzled source column: slot (tid&7) of row r fetches chunk (tid&7)^(r&7)
  int kc = ((tid & 7) ^ ((tid >> 3) & 7)) * 8;       // i*32 doesn't change r&7
  // fragment-read xor key (elements): chunk cc -> slot cc^(l16&7)
  int xr = (l16 & 7) * 8;

  for (int k0 = 0; k0 < K; k0 += BK) {
#pragma unroll
    for (int i = 0; i < NI; ++i)
      gld16(&A[(size_t)(m0 + row + i * 32) * K + k0 + kc],
            (char*)As + (i * 256 + wave * 64) * 16);
#pragma unroll
    for (int j = 0; j < 4; ++j)
      gld16(&Bt[(size_t)(n0 + row + j * 32) * K + k0 + kc],
            (char*)Bs + (j * 256 + wave * 64) * 16);
    __syncthreads();
#pragma unroll
    for (int ks = 0; ks < 2; ++ks) {
      bf16x8 af[NI], bfr[4];
#pragma unroll
      for (int i = 0; i < NI; ++i)
        af[i] = *(const bf16x8*)&As[(wm * (BMT / 2) + i * 16 + l16) * BK +
                                    ((ks * 32 + quad * 8) ^ xr)];
#pragma unroll
      for (int j = 0; j < 4; ++j)
        bfr[j] = *(const bf16x8*)&Bs[(wn * 64 + j * 16 + l16) * BK +
                                     ((ks * 32 + quad * 8) ^ xr)];
#pragma unroll
      for (int i = 0; i < NI; ++i)
#pragma unroll
        for (int j = 0; j < 4; ++j) acc[i][j] = MFMA_BF16(af[i], bfr[j], acc[i][j]);
    }
    __syncthreads();
  }
  // epilogue: D row = quad*4+r, col = lane&15 within each 16x16 tile
#pragma unroll
  for (int i = 0; i < NI; ++i) {
#pragma unroll
    for (int j = 0; j < 4; ++j) {
      int col = n0 + wn * 64 + j * 16 + l16;
      float bv = bias[col];
#pragma unroll
      for (int r = 0; r < 4; ++r) {
        int rw = m0 + wm * (BMT / 2) + i * 16 + quad * 4 + r;
        Cmat[(size_t)rw * N + col] = (TC)(acc[i][j][r] + bv);
      }
    }
  }
}

// ---------------------------------------------------------------------------
// 8-phase qkv GEMM: C[4096][3072] = A[4096][1024] * Bt[3072][1024]^T + bias.
// 256x192 tile, 512 threads (8 waves, 2M x 4N), BK=64 as two K=32 halves.
// Grid 16x16 = 256 blocks = exactly 1 block/CU. (See round-0/1 notes.)
// Epilogue fuses the V transpose: cols >= 2048 go to vt[bh*64+d][t] directly.
// ---------------------------------------------------------------------------
#define BARX do { asm volatile("" ::: "memory"); __builtin_amdgcn_s_barrier(); \
                  asm volatile("" ::: "memory"); } while (0)
#define WLGKM do { asm volatile("s_waitcnt lgkmcnt(0)" ::: "memory"); \
                   __builtin_amdgcn_sched_barrier(0); } while (0)
#define WVM4 asm volatile("s_waitcnt vmcnt(4)" ::: "memory")
#define STA8(SBUF, SKS, T) do { \
    gld16(srcA1 + (size_t)(T) * 64 + (SKS) * 32, (char*)&As[SBUF][SKS][0] + tid * 16); \
    gld16(srcA2 + (size_t)(T) * 64 + (SKS) * 32, (char*)&As[SBUF][SKS][0] + tid * 16 + 8192); \
  } while (0)
#define STB8(SBUF, SKS, T) do { \
    gld16(srcB1 + (size_t)(T) * 64 + (SKS) * 32, (char*)&Bs[SBUF][SKS][0] + tid * 16); \
    gld16(srcB2 + (size_t)(T) * 64 + (SKS) * 32, (char*)&Bs[SBUF][SKS][0] + tid * 16 + 8192); \
  } while (0)
#define LDA4(CBUF, CKS, MQ) do { \
    const __bf16* p_ = &As[CBUF][CKS][(wm * 128 + (MQ) * 64 + l16) * 32 + xrd]; \
    af[0] = *(const bf16x8*)(p_);        af[1] = *(const bf16x8*)(p_ + 512); \
    af[2] = *(const bf16x8*)(p_ + 1024); af[3] = *(const bf16x8*)(p_ + 1536); \
  } while (0)
#define LDB3(CBUF, CKS) do { \
    const __bf16* p_ = &Bs[CBUF][CKS][(wn * 48 + l16) * 32 + xrd]; \
    bfr[0] = *(const bf16x8*)(p_);       bfr[1] = *(const bf16x8*)(p_ + 512); \
    bfr[2] = *(const bf16x8*)(p_ + 1024); \
  } while (0)
#define MM12(MQ) do { \
    __builtin_amdgcn_s_setprio(1); \
    _Pragma("unroll") for (int mi_ = 0; mi_ < 4; ++mi_) \
    _Pragma("unroll") for (int nj_ = 0; nj_ < 3; ++nj_) \
      acc[(MQ) * 4 + mi_][nj_] = MFMA_BF16(af[mi_], bfr[nj_], acc[(MQ) * 4 + mi_][nj_]); \
    __builtin_amdgcn_s_setprio(0); \
  } while (0)

__global__ __launch_bounds__(512, 2) void gemm_qkv_8ph(
    const __bf16* __restrict__ A, const __bf16* __restrict__ Bt,
    const float* __restrict__ bias, __bf16* __restrict__ qkv,
    __bf16* __restrict__ vt) {
  constexpr int GK = 1024, GN = 3072, NT = 16;  // K, N, K-tiles
  // [buf][khalf][row*32+col]; 16 KiB per region, 128 KiB total.
  __shared__ __align__(16) __bf16 As[2][2][256 * 32];
  __shared__ __align__(16) __bf16 Bs[2][2][256 * 32];  // rows 192..255 = pad
  const int tid = threadIdx.x;
  const int wave = tid >> 6, lane = tid & 63;
  const int l16 = lane & 15, quad = lane >> 4;
  const int wm = wave >> 2, wn = wave & 3;
  const int m0 = blockIdx.y * 256, n0 = blockIdx.x * 192;

  // staging: thread -> (row=tid>>2, slot=tid&3); source chunk = slot^((row>>1)&3)
  const int row0 = tid >> 2;                       // 0..127 (+128 on call 2)
  const int kc = (((tid & 3) ^ ((row0 >> 1) & 3)) * 8);
  // fragment-read xor key: chunk = quad ^ ((row>>1)&3); row>>1 dep reduces to l16
  const int xrd = (quad ^ ((l16 >> 1) & 3)) * 8;

  const __bf16* srcA1 = A + (size_t)(m0 + row0) * GK + kc;
  const __bf16* srcA2 = srcA1 + (size_t)128 * GK;
  const __bf16* srcB1 = Bt + (size_t)(n0 + row0) * GK + kc;
  const int br2 = (row0 + 128 < 192) ? row0 + 128 : 191;  // clamp pad rows
  const __bf16* srcB2 = Bt + (size_t)(n0 + br2) * GK + kc;

  f32x4 acc[8][3];
#pragma unroll
  for (int m = 0; m < 8; ++m)
#pragma unroll
    for (int n = 0; n < 3; ++n) acc[m][n] = (f32x4){0.f, 0.f, 0.f, 0.f};

  // prologue: tile0 (both halves) + tile1 ks0; wait tile0, keep t1ks0 in flight
  STA8(0, 0, 0); STB8(0, 0, 0);
  STA8(0, 1, 0); STB8(0, 1, 0);
  STA8(1, 0, 1); STB8(1, 0, 1);
  WVM4;
  BARX;

  bf16x8 af[4], bfr[3];
#pragma unroll 1
  for (int i = 0; i < NT / 2; ++i) {
    const int v = 2 * i + 1;
    const int t2 = (2 * i + 2 < NT) ? 2 * i + 2 : NT - 1;  // clamped: junk
    const int t3 = (2 * i + 3 < NT) ? 2 * i + 3 : NT - 1;  // staged, never read
    // ph1: compute (buf0, ks0, Mquad0)
    LDA4(0, 0, 0); LDB3(0, 0); STA8(1, 1, v);
    BARX; WLGKM; MM12(0); BARX;
    // ph2: (buf0, ks0, Mquad1); B frags reused
    LDA4(0, 0, 1); STB8(1, 1, v);
    BARX; WLGKM; MM12(1); BARX;
    // ph3: (buf0, ks1, Mquad0); buf0.ks0 free after ph2 -> restage
    LDA4(0, 1, 0); LDB3(0, 1); STA8(0, 0, t2);
    BARX; WLGKM; MM12(0); BARX;
    // ph4: (buf0, ks1, Mquad1); counted wait: tile v fully landed, 2 halves in flight
    LDA4(0, 1, 1); STB8(0, 0, t2);
    BARX; WLGKM; MM12(1); WVM4; BARX;
    // ph5: (buf1, ks0, Mquad0); buf0.ks1 free after ph4 -> restage
    LDA4(1, 0, 0); LDB3(1, 0); STA8(0, 1, t2);
    BARX; WLGKM; MM12(0); BARX;
    // ph6
    LDA4(1, 0, 1); STB8(0, 1, t2);
    BARX; WLGKM; MM12(1); BARX;
    // ph7: (buf1, ks1, Mquad0); buf1.ks0 free after ph6 -> restage
    LDA4(1, 1, 0); LDB3(1, 1); STA8(1, 0, t3);
    BARX; WLGKM; MM12(0); BARX;
    // ph8; counted wait: tile 2i+2 fully landed for next iteration's ph1
    LDA4(1, 1, 1); STB8(1, 0, t3);
    BARX; WLGKM; MM12(1); WVM4; BARX;
  }

  // epilogue: D row = quad*4+r (M), col = l16 (N). V cols write vt directly.
#pragma unroll
  for (int n = 0; n < 3; ++n) {
    const int c0 = n0 + wn * 48 + n * 16;  // wave-uniform; 2048 is 16-aligned
    const int col = c0 + l16;
    const float bv = bias[col];
    if (c0 < 2048) {
#pragma unroll
      for (int m = 0; m < 8; ++m) {
        const int rw = m0 + wm * 128 + m * 16 + quad * 4;
#pragma unroll
        for (int r = 0; r < 4; ++r)
          qkv[(size_t)(rw + r) * GN + col] = (__bf16)(acc[m][n][r] + bv);
      }
    } else {
      const int h = (col - 2048) >> 6, d = col & 63;
#pragma unroll
      for (int m = 0; m < 8; ++m) {
        const int t0 = m0 + wm * 128 + m * 16 + quad * 4;
        const int b = t0 >> 11, tt = t0 & 2047;
        bf16x4 pb;
#pragma unroll
        for (int r = 0; r < 4; ++r) pb[r] = (__bf16)(acc[m][n][r] + bv);
        *(bf16x4*)&vt[(size_t)((b * 16 + h) * 64 + d) * 2048 + tt] = pb;
      }
    }
  }
}

// ---------------------------------------------------------------------------
// Causal flash attention, 32x32 MFMA, in-register P (no Ps LDS).
// Round 7: round-6 passed (fragment math VERIFIED) but was slower -- occupancy
// 11% (avg 4.1 waves/CU from the triangular-drain grid; 2-wave blocks).
// Fix occupancy shape, keep the verified per-wave body:
//   - 4-wave blocks, waves = (qh, kh): wave (qh,kh) computes key-subtile kh
//     (64 keys of a 128-key iteration) for q-rows qh*32+l32. K/V subtile read
//     by 2 waves only -> LDS amplification stays 2x; barriers per key halved.
//     Partial O/l (additive under no-max softmax) combined across kh via LDS
//     once per phase.
//   - pairing: grid (32 bh, 16 p); phase A qt=p, phase B qt=31-p ->
//     ceil((p+1)/2)+ceil((32-p)/2) = 17 iterations for EVERY block. 512
//     blocks x 64 KB LDS = exactly 2 blocks/CU, 8 waves/CU, constant (no
//     drain tail). id%8 = bh%8 -> one bh per XCD (K/V L2-resident).
//   - swizzle upgraded: chunk ^= (row&7) ^ ((row>>3)&3), applied BOTH to the
//     gld16 source permute and the fragment read (same involution both sides,
//     rule 21) -> removes the 4-way ds_read_b128 conflict across 32 rows.
//   - skip rule: wave computes only if ktile=2*it+kh <= qt (uniform branch;
//     fully-masked diagonal overflow subtile is skipped, barriers still hit).
// ---------------------------------------------------------------------------
#define CVTPK(D, LO, HI) \
  asm("v_cvt_pk_bf16_f32 %0, %1, %2" : "=v"(D) : "v"(LO), "v"(HI))
#define SWAP32(DST, SRC) \
  asm("v_permlane32_swap_b32 %0, %1" : "+v"(DST), "+v"(SRC))

__device__ __forceinline__ bf16x8 mk8(u32 a, u32 b, u32 c, u32 d) {
  union { u32 u[4]; bf16x8 h; } x;
  x.u[0] = a; x.u[1] = b; x.u[2] = c; x.u[3] = d;
  return x.h;
}

__global__ __launch_bounds__(256, 2) void attn_causal(
    const __bf16* __restrict__ qkv, const __bf16* __restrict__ vt,
    __bf16* __restrict__ y) {
  __shared__ __align__(16) __bf16 Kb[2][2][64 * 64];  // [buf][khalf][key][dim-swz]
  __shared__ __align__(16) __bf16 Vb[2][2][64 * 64];  // [buf][khalf][dim][key-swz]
  const int tid = threadIdx.x;
  const int wave = tid >> 6, lane = tid & 63;
  const int l32 = lane & 31, hi = lane >> 5;
  const int qh = wave >> 1, kh = wave & 1;
  const int bh = blockIdx.x;
  const int b = bh >> 4, h = bh & 15;
  const int RS = 3072;
  const int p = (int)blockIdx.y;

  // staging: row8 = tid>>3 (0..31; +32 for i=1); slot tid&7 of row r holds
  // source chunk slot^(r&7)^((r>>3)&3)  [r&31 == row8 for both i]
  const int row8 = tid >> 3;
  const int kcs = (((tid & 7) ^ (row8 & 7) ^ ((row8 >> 3) & 3)) * 8);
  const __bf16* kbase = qkv + (size_t)(b * 2048) * RS + 1024 + h * 64 + kcs;
  const __bf16* vbase = vt + (size_t)(bh * 64) * 2048 + kcs;
  // fragment-read xor key (chunks); rows l32 and 32+l32 share it
  const int xr = (l32 & 7) ^ ((l32 >> 3) & 3);
  float* sc = (float*)Vb;  // combine scratch (reused after each phase loop)

#pragma unroll 1
  for (int phase = 0; phase < 2; ++phase) {
    const int qt = phase ? 31 - p : p;
    const int nit = (qt + 2) >> 1;  // ceil((qt+1)/2) 128-key iterations

    // Q fragments (B-operand): col=q=l32, k=hi*8+e
    const __bf16* qp = qkv +
        (size_t)(b * 2048 + qt * 64 + qh * 32 + l32) * RS + h * 64 + hi * 8;
    bf16x8 qf[4];
#pragma unroll
    for (int kc = 0; kc < 4; ++kc) qf[kc] = *(const bf16x8*)(qp + kc * 16);

    float l4[4] = {0.f, 0.f, 0.f, 0.f};
    f32x16 o0, o1;
#pragma unroll
    for (int r = 0; r < 16; ++r) { o0[r] = 0.f; o1[r] = 0.f; }

    // prologue: stage 128-key tile 0 (both halves) into buf 0
#pragma unroll
    for (int s = 0; s < 2; ++s)
#pragma unroll
      for (int i = 0; i < 2; ++i) {
        gld16(kbase + (size_t)(s * 64 + i * 32 + row8) * RS,
              (char*)Kb[0][s] + (i * 256 + tid) * 16);
        gld16(vbase + (size_t)(i * 32 + row8) * 2048 + s * 64,
              (char*)Vb[0][s] + (i * 256 + tid) * 16);
      }
    __syncthreads();

    for (int it = 0; it < nit; ++it) {
      const int cur = it & 1;
      if (it + 1 < nit) {  // guarded: no OOB prefetch
        const int kb2 = (it + 1) * 128;
#pragma unroll
        for (int s = 0; s < 2; ++s)
#pragma unroll
          for (int i = 0; i < 2; ++i) {
            gld16(kbase + (size_t)(kb2 + s * 64 + i * 32 + row8) * RS,
                  (char*)Kb[cur ^ 1][s] + (i * 256 + tid) * 16);
            gld16(vbase + (size_t)(i * 32 + row8) * 2048 + kb2 + s * 64,
                  (char*)Vb[cur ^ 1][s] + (i * 256 + tid) * 16);
          }
      }

      const int ktile = 2 * it + kh;
      if (ktile <= qt) {  // wave-uniform; skip fully-masked overflow subtile
        // S^T = K Q^T : c[kb][r] = S^T[key=kb*32+(r&3)+8*(r>>2)+4*hi][q=l32]
        f32x16 c0, c1;
#pragma unroll
        for (int r = 0; r < 16; ++r) { c0[r] = 0.f; c1[r] = 0.f; }
        __builtin_amdgcn_s_setprio(1);
#pragma unroll
        for (int kc = 0; kc < 4; ++kc) {
          const int sw = ((kc * 2 + hi) ^ xr) << 3;
          bf16x8 kf0 = *(const bf16x8*)&Kb[cur][kh][l32 * 64 + sw];
          bf16x8 kf1 = *(const bf16x8*)&Kb[cur][kh][(32 + l32) * 64 + sw];
          c0 = MFMA32(kf0, qf[kc], c0);
          c1 = MFMA32(kf1, qf[kc], c1);
        }
        __builtin_amdgcn_s_setprio(0);

        // causal mask only on the diagonal subtile
        if (ktile == qt) {
          const int qloc = qh * 32 + l32;
#pragma unroll
          for (int r = 0; r < 16; ++r) {
            const int kl = (r & 3) + 8 * (r >> 2) + 4 * hi;
            if (kl > qloc) c0[r] = NEG_INF;
            if (32 + kl > qloc) c1[r] = NEG_INF;
          }
        }

        // softmax + in-register pack to PV B-frags (SWAP32 dir verified r6)
        bf16x8 pb[4];
#pragma unroll
        for (int kb = 0; kb < 2; ++kb) {
          float pv[16];
#pragma unroll
          for (int r = 0; r < 16; ++r) {
            const float sv = (kb ? c1[r] : c0[r]);
            pv[r] = __builtin_amdgcn_exp2f(sv * SCL);
            l4[r & 3] += pv[r];
          }
          u32 a0, a1, b0, b1;
          CVTPK(a0, pv[0], pv[1]);   CVTPK(a1, pv[2], pv[3]);
          CVTPK(b0, pv[4], pv[5]);   CVTPK(b1, pv[6], pv[7]);
          SWAP32(a0, b0); SWAP32(a1, b1);
          pb[kb * 2 + 0] = mk8(a0, a1, b0, b1);
          CVTPK(a0, pv[8], pv[9]);   CVTPK(a1, pv[10], pv[11]);
          CVTPK(b0, pv[12], pv[13]); CVTPK(b1, pv[14], pv[15]);
          SWAP32(a0, b0); SWAP32(a1, b1);
          pb[kb * 2 + 1] = mk8(a0, a1, b0, b1);
        }

        // O^T += V^T P : o[db][r] = O^T[d=db*32+(r&3)+8*(r>>2)+4*hi][q=l32]
        __builtin_amdgcn_s_setprio(1);
#pragma unroll
        for (int kc = 0; kc < 4; ++kc) {
          const int sw = ((kc * 2 + hi) ^ xr) << 3;
          bf16x8 vf0 = *(const bf16x8*)&Vb[cur][kh][l32 * 64 + sw];
          bf16x8 vf1 = *(const bf16x8*)&Vb[cur][kh][(32 + l32) * 64 + sw];
          o0 = MFMA32(vf0, pb[kc], o0);
          o1 = MFMA32(vf1, pb[kc], o1);
        }
        __builtin_amdgcn_s_setprio(0);
      }
      __syncthreads();  // drains DMA; next tile ready
    }

    // cross-wave (key-half) combine: O and l are additive (no-max softmax)
    float lred = (l4[0] + l4[1]) + (l4[2] + l4[3]);
    lred += __shfl_xor(lred, 32);
    if (kh == 1) {
      float* ob = sc + qh * 2048;
#pragma unroll
      for (int r = 0; r < 16; ++r) {
        ob[r * 64 + lane] = o0[r];
        ob[1024 + r * 64 + lane] = o1[r];
      }
      if (lane < 32) sc[4096 + qh * 32 + lane] = lred;
    }
    __syncthreads();
    if (kh == 0) {
      const float* ob = sc + qh * 2048;
      lred += sc[4096 + qh * 32 + l32];
      const float inv = 1.f / lred;
      const int orow = b * 2048 + qt * 64 + qh * 32 + l32;
      __bf16* yb = y + (size_t)orow * 1024 + h * 64 + hi * 4;
#pragma unroll
      for (int db = 0; db < 2; ++db) {
#pragma unroll
        for (int g = 0; g < 4; ++g) {
          bf16x4 w;
#pragma unroll
          for (int j = 0; j < 4; ++j) {
            const float v = (db ? o1[g * 4 + j] : o0[g * 4 + j]) +
                            ob[db * 1024 + (g * 4 + j) * 64 + lane];
            w[j] = (__bf16)(v * inv);
          }
          *(bf16x4*)&yb[db * 32 + g * 8] = w;
        }
      }
    }
    __syncthreads();  // scratch free before next phase's staging
  }
}

// ---------------------------------------------------------------------------
extern "C" void kernel_launch(void* const* d_in, const int* in_sizes, int n_in,
                              void* d_out, int out_size, void* d_ws, size_t ws_size,
                              hipStream_t stream) {
  (void)in_sizes; (void)n_in; (void)out_size; (void)ws_size;
  const float* x      = (const float*)d_in[0];  // [2,2048,1024] fp32
  const float* w_attn = (const float*)d_in[1];  // [1024,3072]
  const float* b_attn = (const float*)d_in[2];  // [3072]
  const float* w_proj = (const float*)d_in[3];  // [1024,1024]
  const float* b_proj = (const float*)d_in[4];  // [1024]
  float* out = (float*)d_out;                   // [2,2048,1024] fp32

  __bf16* wt_attn = (__bf16*)d_ws;                       // [3072][1024]
  __bf16* wt_proj = wt_attn + (size_t)3072 * 1024;       // [1024][1024]
  __bf16* qkv     = wt_proj + (size_t)1024 * 1024;       // [4096][3072]
  __bf16* ybuf    = qkv + (size_t)4096 * 3072;           // [4096][1024]
  __bf16* vtbuf   = ybuf + (size_t)4096 * 1024;          // [32*64][2048]

  // x -> bf16, staged in ybuf (attention overwrites it later; same stream)
  cast_f32_bf16<<<4096 * 1024 / 2048, 256, 0, stream>>>(x, ybuf, 4096 * 1024);

  transpose_f32_bf16<<<dim3(3072 / 32, 1024 / 32), 256, 0, stream>>>(w_attn, wt_attn, 1024, 3072);
  transpose_f32_bf16<<<dim3(1024 / 32, 1024 / 32), 256, 0, stream>>>(w_proj, wt_proj, 1024, 1024);

  // qkv = x @ w_attn + b_attn; V columns written transposed into vtbuf
  // (8-phase 256x192 tile; grid 16x16 = 256 blocks = 1/CU)
  gemm_qkv_8ph<<<dim3(3072 / 192, 4096 / 256), 512, 0, stream>>>(
      ybuf, wt_attn, b_attn, qkv, vtbuf);

  // y = causal_attention(qkv, vt), overwrites ybuf
  // (512 blocks of 256 threads, uniform 17 iters, 2 blocks/CU = 8 waves/CU)
  attn_causal<<<dim3(32, 16), 256, 0, stream>>>(qkv, vtbuf, ybuf);

  // out = y @ w_proj + b_proj   (512 blocks, BM=64 for occupancy)
  gemm_bt_bias<64, float><<<dim3(1024 / BN, 4096 / 64), 256, 0, stream>>>(
      ybuf, wt_proj, b_proj, out, 4096, 1024, 1024);
}

// Round 8
// 169.230 us; speedup vs baseline: 1.0916x; 1.0331x over previous
//
#include <hip/hip_runtime.h>

typedef __bf16 bf16x8 __attribute__((ext_vector_type(8)));
typedef __bf16 bf16x4 __attribute__((ext_vector_type(4)));
typedef float  f32x4  __attribute__((ext_vector_type(4)));
typedef float  f32x16 __attribute__((ext_vector_type(16)));
typedef unsigned int u32;

#define MFMA_BF16(a, b, c) __builtin_amdgcn_mfma_f32_16x16x32_bf16((a), (b), (c), 0, 0, 0)
#define MFMA32(a, b, c) __builtin_amdgcn_mfma_f32_32x32x16_bf16((a), (b), (c), 0, 0, 0)
#define NEG_INF (-1e30f)
// softmax scale folded with log2(e): exp(s*0.125) == exp2(s*0.125*1.442695)
#define SCL 0.18033688f

__device__ __forceinline__ void gld16(const void* g, void* l) {
  __builtin_amdgcn_global_load_lds(
      (const __attribute__((address_space(1))) void*)g,
      (__attribute__((address_space(3))) void*)l, 16, 0, 0);
}

// ---------------------------------------------------------------------------
// Cast fp32 -> bf16, 8 elems/thread.
// ---------------------------------------------------------------------------
__global__ void cast_f32_bf16(const float* __restrict__ in,
                              __bf16* __restrict__ out, int n) {
  int i = (blockIdx.x * 256 + threadIdx.x) * 8;
  if (i >= n) return;
  float4 a = *(const float4*)&in[i];
  float4 b = *(const float4*)&in[i + 4];
  bf16x8 v;
  v[0] = (__bf16)a.x; v[1] = (__bf16)a.y; v[2] = (__bf16)a.z; v[3] = (__bf16)a.w;
  v[4] = (__bf16)b.x; v[5] = (__bf16)b.y; v[6] = (__bf16)b.z; v[7] = (__bf16)b.w;
  *(bf16x8*)&out[i] = v;
}

// ---------------------------------------------------------------------------
// Transpose: in [R][C] fp32 -> out [C][R] bf16. 32x32 tiles, 256 threads.
// ---------------------------------------------------------------------------
__global__ void transpose_f32_bf16(const float* __restrict__ in,
                                   __bf16* __restrict__ out, int R, int C) {
  __shared__ float t[32][33];
  int tx = threadIdx.x & 31, ty = threadIdx.x >> 5;  // 32 x 8
  int x = blockIdx.x * 32 + tx;
  int y0 = blockIdx.y * 32 + ty;
#pragma unroll
  for (int i = 0; i < 4; ++i)
    t[ty + 8 * i][tx] = in[(size_t)(y0 + 8 * i) * C + x];
  __syncthreads();
  int x2 = blockIdx.y * 32 + tx;
#pragma unroll
  for (int i = 0; i < 4; ++i)
    out[(size_t)(blockIdx.x * 32 + ty + 8 * i) * R + x2] = (__bf16)t[tx][ty + 8 * i];
}

// ---------------------------------------------------------------------------
// GEMM: C[M][N] = A[M][K]*Bt[N][K]^T + bias[N]. A,Bt bf16, fp32 accum.
// m97 structure + XOR-swizzled LDS (source-permuted gld16; conflict-free).
// Still used for the proj GEMM.
// ---------------------------------------------------------------------------
#define BN 128
#define BK 64

template <int BMT, typename TC>
__global__ __launch_bounds__(256) void gemm_bt_bias(
    const __bf16* __restrict__ A, const __bf16* __restrict__ Bt,
    const float* __restrict__ bias, TC* __restrict__ Cmat,
    int M, int N, int K) {
  constexpr int NI = BMT / 32;  // A chunks per thread; MFMA row-tiles per wave
  __shared__ __align__(16) __bf16 As[BMT * BK];
  __shared__ __align__(16) __bf16 Bs[BN * BK];
  int tid = threadIdx.x;
  int wave = tid >> 6, lane = tid & 63;
  int l16 = lane & 15, quad = lane >> 4;
  int wm = wave >> 1, wn = wave & 1;
  int m0 = blockIdx.y * BMT, n0 = blockIdx.x * BN;

  f32x4 acc[NI][4];
#pragma unroll
  for (int i = 0; i < NI; ++i)
#pragma unroll
    for (int j = 0; j < 4; ++j) acc[i][j] = (f32x4){0.f, 0.f, 0.f, 0.f};

  int row = tid >> 3;                                // 0..31 (+32*i)
  // swizzled source column: slot (tid&7) of row r fetches chunk (tid&7)^(r&7)
  int kc = ((tid & 7) ^ ((tid >> 3) & 7)) * 8;       // i*32 doesn't change r&7
  // fragment-read xor key (elements): chunk cc -> slot cc^(l16&7)
  int xr = (l16 & 7) * 8;

  for (int k0 = 0; k0 < K; k0 += BK) {
#pragma unroll
    for (int i = 0; i < NI; ++i)
      gld16(&A[(size_t)(m0 + row + i * 32) * K + k0 + kc],
            (char*)As + (i * 256 + wave * 64) * 16);
#pragma unroll
    for (int j = 0; j < 4; ++j)
      gld16(&Bt[(size_t)(n0 + row + j * 32) * K + k0 + kc],
            (char*)Bs + (j * 256 + wave * 64) * 16);
    __syncthreads();
#pragma unroll
    for (int ks = 0; ks < 2; ++ks) {
      bf16x8 af[NI], bfr[4];
#pragma unroll
      for (int i = 0; i < NI; ++i)
        af[i] = *(const bf16x8*)&As[(wm * (BMT / 2) + i * 16 + l16) * BK +
                                    ((ks * 32 + quad * 8) ^ xr)];
#pragma unroll
      for (int j = 0; j < 4; ++j)
        bfr[j] = *(const bf16x8*)&Bs[(wn * 64 + j * 16 + l16) * BK +
                                     ((ks * 32 + quad * 8) ^ xr)];
#pragma unroll
      for (int i = 0; i < NI; ++i)
#pragma unroll
        for (int j = 0; j < 4; ++j) acc[i][j] = MFMA_BF16(af[i], bfr[j], acc[i][j]);
    }
    __syncthreads();
  }
  // epilogue: D row = quad*4+r, col = lane&15 within each 16x16 tile
#pragma unroll
  for (int i = 0; i < NI; ++i) {
#pragma unroll
    for (int j = 0; j < 4; ++j) {
      int col = n0 + wn * 64 + j * 16 + l16;
      float bv = bias[col];
#pragma unroll
      for (int r = 0; r < 4; ++r) {
        int rw = m0 + wm * (BMT / 2) + i * 16 + quad * 4 + r;
        Cmat[(size_t)rw * N + col] = (TC)(acc[i][j][r] + bv);
      }
    }
  }
}

// ---------------------------------------------------------------------------
// 8-phase qkv GEMM: C[4096][3072] = A[4096][1024] * Bt[3072][1024]^T + bias.
// 256x192 tile, 512 threads (8 waves, 2M x 4N), BK=64 as two K=32 halves.
// Grid 16x16 = 256 blocks = exactly 1 block/CU. (See round-0/1 notes.)
// Epilogue fuses the V transpose: cols >= 2048 go to vt[bh*64+d][t] directly.
// ---------------------------------------------------------------------------
#define BARX do { asm volatile("" ::: "memory"); __builtin_amdgcn_s_barrier(); \
                  asm volatile("" ::: "memory"); } while (0)
#define WLGKM do { asm volatile("s_waitcnt lgkmcnt(0)" ::: "memory"); \
                   __builtin_amdgcn_sched_barrier(0); } while (0)
#define WVM4 asm volatile("s_waitcnt vmcnt(4)" ::: "memory")
#define STA8(SBUF, SKS, T) do { \
    gld16(srcA1 + (size_t)(T) * 64 + (SKS) * 32, (char*)&As[SBUF][SKS][0] + tid * 16); \
    gld16(srcA2 + (size_t)(T) * 64 + (SKS) * 32, (char*)&As[SBUF][SKS][0] + tid * 16 + 8192); \
  } while (0)
#define STB8(SBUF, SKS, T) do { \
    gld16(srcB1 + (size_t)(T) * 64 + (SKS) * 32, (char*)&Bs[SBUF][SKS][0] + tid * 16); \
    gld16(srcB2 + (size_t)(T) * 64 + (SKS) * 32, (char*)&Bs[SBUF][SKS][0] + tid * 16 + 8192); \
  } while (0)
#define LDA4(CBUF, CKS, MQ) do { \
    const __bf16* p_ = &As[CBUF][CKS][(wm * 128 + (MQ) * 64 + l16) * 32 + xrd]; \
    af[0] = *(const bf16x8*)(p_);        af[1] = *(const bf16x8*)(p_ + 512); \
    af[2] = *(const bf16x8*)(p_ + 1024); af[3] = *(const bf16x8*)(p_ + 1536); \
  } while (0)
#define LDB3(CBUF, CKS) do { \
    const __bf16* p_ = &Bs[CBUF][CKS][(wn * 48 + l16) * 32 + xrd]; \
    bfr[0] = *(const bf16x8*)(p_);       bfr[1] = *(const bf16x8*)(p_ + 512); \
    bfr[2] = *(const bf16x8*)(p_ + 1024); \
  } while (0)
#define MM12(MQ) do { \
    __builtin_amdgcn_s_setprio(1); \
    _Pragma("unroll") for (int mi_ = 0; mi_ < 4; ++mi_) \
    _Pragma("unroll") for (int nj_ = 0; nj_ < 3; ++nj_) \
      acc[(MQ) * 4 + mi_][nj_] = MFMA_BF16(af[mi_], bfr[nj_], acc[(MQ) * 4 + mi_][nj_]); \
    __builtin_amdgcn_s_setprio(0); \
  } while (0)

__global__ __launch_bounds__(512, 2) void gemm_qkv_8ph(
    const __bf16* __restrict__ A, const __bf16* __restrict__ Bt,
    const float* __restrict__ bias, __bf16* __restrict__ qkv,
    __bf16* __restrict__ vt) {
  constexpr int GK = 1024, GN = 3072, NT = 16;  // K, N, K-tiles
  // [buf][khalf][row*32+col]; 16 KiB per region, 128 KiB total.
  __shared__ __align__(16) __bf16 As[2][2][256 * 32];
  __shared__ __align__(16) __bf16 Bs[2][2][256 * 32];  // rows 192..255 = pad
  const int tid = threadIdx.x;
  const int wave = tid >> 6, lane = tid & 63;
  const int l16 = lane & 15, quad = lane >> 4;
  const int wm = wave >> 2, wn = wave & 3;
  const int m0 = blockIdx.y * 256, n0 = blockIdx.x * 192;

  // staging: thread -> (row=tid>>2, slot=tid&3); source chunk = slot^((row>>1)&3)
  const int row0 = tid >> 2;                       // 0..127 (+128 on call 2)
  const int kc = (((tid & 3) ^ ((row0 >> 1) & 3)) * 8);
  // fragment-read xor key: chunk = quad ^ ((row>>1)&3); row>>1 dep reduces to l16
  const int xrd = (quad ^ ((l16 >> 1) & 3)) * 8;

  const __bf16* srcA1 = A + (size_t)(m0 + row0) * GK + kc;
  const __bf16* srcA2 = srcA1 + (size_t)128 * GK;
  const __bf16* srcB1 = Bt + (size_t)(n0 + row0) * GK + kc;
  const int br2 = (row0 + 128 < 192) ? row0 + 128 : 191;  // clamp pad rows
  const __bf16* srcB2 = Bt + (size_t)(n0 + br2) * GK + kc;

  f32x4 acc[8][3];
#pragma unroll
  for (int m = 0; m < 8; ++m)
#pragma unroll
    for (int n = 0; n < 3; ++n) acc[m][n] = (f32x4){0.f, 0.f, 0.f, 0.f};

  // prologue: tile0 (both halves) + tile1 ks0; wait tile0, keep t1ks0 in flight
  STA8(0, 0, 0); STB8(0, 0, 0);
  STA8(0, 1, 0); STB8(0, 1, 0);
  STA8(1, 0, 1); STB8(1, 0, 1);
  WVM4;
  BARX;

  bf16x8 af[4], bfr[3];
#pragma unroll 1
  for (int i = 0; i < NT / 2; ++i) {
    const int v = 2 * i + 1;
    const int t2 = (2 * i + 2 < NT) ? 2 * i + 2 : NT - 1;  // clamped: junk
    const int t3 = (2 * i + 3 < NT) ? 2 * i + 3 : NT - 1;  // staged, never read
    // ph1: compute (buf0, ks0, Mquad0)
    LDA4(0, 0, 0); LDB3(0, 0); STA8(1, 1, v);
    BARX; WLGKM; MM12(0); BARX;
    // ph2: (buf0, ks0, Mquad1); B frags reused
    LDA4(0, 0, 1); STB8(1, 1, v);
    BARX; WLGKM; MM12(1); BARX;
    // ph3: (buf0, ks1, Mquad0); buf0.ks0 free after ph2 -> restage
    LDA4(0, 1, 0); LDB3(0, 1); STA8(0, 0, t2);
    BARX; WLGKM; MM12(0); BARX;
    // ph4: (buf0, ks1, Mquad1); counted wait: tile v fully landed, 2 halves in flight
    LDA4(0, 1, 1); STB8(0, 0, t2);
    BARX; WLGKM; MM12(1); WVM4; BARX;
    // ph5: (buf1, ks0, Mquad0); buf0.ks1 free after ph4 -> restage
    LDA4(1, 0, 0); LDB3(1, 0); STA8(0, 1, t2);
    BARX; WLGKM; MM12(0); BARX;
    // ph6
    LDA4(1, 0, 1); STB8(0, 1, t2);
    BARX; WLGKM; MM12(1); BARX;
    // ph7: (buf1, ks1, Mquad0); buf1.ks0 free after ph6 -> restage
    LDA4(1, 1, 0); LDB3(1, 1); STA8(1, 0, t3);
    BARX; WLGKM; MM12(0); BARX;
    // ph8; counted wait: tile 2i+2 fully landed for next iteration's ph1
    LDA4(1, 1, 1); STB8(1, 0, t3);
    BARX; WLGKM; MM12(1); WVM4; BARX;
  }

  // epilogue: D row = quad*4+r (M), col = l16 (N). V cols write vt directly.
#pragma unroll
  for (int n = 0; n < 3; ++n) {
    const int c0 = n0 + wn * 48 + n * 16;  // wave-uniform; 2048 is 16-aligned
    const int col = c0 + l16;
    const float bv = bias[col];
    if (c0 < 2048) {
#pragma unroll
      for (int m = 0; m < 8; ++m) {
        const int rw = m0 + wm * 128 + m * 16 + quad * 4;
#pragma unroll
        for (int r = 0; r < 4; ++r)
          qkv[(size_t)(rw + r) * GN + col] = (__bf16)(acc[m][n][r] + bv);
      }
    } else {
      const int h = (col - 2048) >> 6, d = col & 63;
#pragma unroll
      for (int m = 0; m < 8; ++m) {
        const int t0 = m0 + wm * 128 + m * 16 + quad * 4;
        const int b = t0 >> 11, tt = t0 & 2047;
        bf16x4 pb;
#pragma unroll
        for (int r = 0; r < 4; ++r) pb[r] = (__bf16)(acc[m][n][r] + bv);
        *(bf16x4*)&vt[(size_t)((b * 16 + h) * 64 + d) * 2048 + tt] = pb;
      }
    }
  }
}

// ---------------------------------------------------------------------------
// Causal flash attention, 32x32 MFMA, in-register P (no Ps LDS).
// Round 8: round-7 was DEPENDENCY-CHAIN-BOUND: wall 5000 cyc/iter vs ~2000
// busiest-pipe; 8 waves/CU with barrier-locked phases -> both waves per SIMD
// contend in the same phase. Fix = 2x the wave pool + shorten the chain:
//   - 8-wave (512-thr) blocks: waves (qh 0..3, kh 0..1); block owns 128
//     q-rows. 512 blocks x 8 waves = 4096 waves = EXACTLY 16 waves/CU
//     (4/SIMD) at 2 blocks/CU (LDS 64 KB, launch_bounds(512,4) caps VGPR
//     at 128; body uses ~70). Staged bytes per unit work HALVE (tile serves
//     128 q-rows).
//   - balance: nit = qb+1; qb = by<8 ? 15-by : by-8 -> big blocks dispatch
//     first AND round-robin partners (c, c+256) sum to 17 iters on every CU.
//   - chain: SM(kb0) -> PV(kc0,1) -> SM(kb1) -> PV(kc2,3) so PV MFMAs overlap
//     the second softmax half's VALU.
// Per-wave fragment math identical to round 6/7 (verified incl. SWAP32 dir).
// ---------------------------------------------------------------------------
#define CVTPK(D, LO, HI) \
  asm("v_cvt_pk_bf16_f32 %0, %1, %2" : "=v"(D) : "v"(LO), "v"(HI))
#define SWAP32(DST, SRC) \
  asm("v_permlane32_swap_b32 %0, %1" : "+v"(DST), "+v"(SRC))

__device__ __forceinline__ bf16x8 mk8(u32 a, u32 b, u32 c, u32 d) {
  union { u32 u[4]; bf16x8 h; } x;
  x.u[0] = a; x.u[1] = b; x.u[2] = c; x.u[3] = d;
  return x.h;
}

__global__ __launch_bounds__(512, 4) void attn_causal(
    const __bf16* __restrict__ qkv, const __bf16* __restrict__ vt,
    __bf16* __restrict__ y) {
  // smem[kv][buf][khalf][64 rows][8 slots x 16B]; 64 KB total.
  __shared__ __align__(16) __bf16 smem[2][2][2][64 * 64];
  const int tid = threadIdx.x;
  const int wave = tid >> 6, lane = tid & 63;
  const int l32 = lane & 31, hi = lane >> 5;
  const int qh = wave >> 1, kh = wave & 1;
  const int bh = blockIdx.x;
  const int b = bh >> 4, h = bh & 15;
  const int RS = 3072;
  const int by = (int)blockIdx.y;
  const int qb = (by < 8) ? 15 - by : by - 8;   // big first; rr-pairs sum 15
  const int nit = qb + 1;                        // 128-key iterations
  const int ktmax = 2 * qb + (qh >> 1);          // last 64-key tile this wave

  // staging: row = tid>>3 (0..63), slot tid&7 holds source chunk
  // slot^(row&7)^((row>>3)&3); one gld16 per thread per 8KB subtile.
  const int row8 = tid >> 3;
  const int kcs = (((tid & 7) ^ (row8 & 7) ^ ((row8 >> 3) & 3)) * 8);
  const __bf16* kbase = qkv + (size_t)(b * 2048) * RS + 1024 + h * 64 + kcs;
  const __bf16* vbase = vt + (size_t)(bh * 64) * 2048 + kcs;
  // fragment-read xor key (chunks); rows l32 and 32+l32 share it
  const int xr = (l32 & 7) ^ ((l32 >> 3) & 3);

  // Q fragments (B-operand): col=q=l32, k=hi*8+e
  const __bf16* qp = qkv +
      (size_t)(b * 2048 + qb * 128 + qh * 32 + l32) * RS + h * 64 + hi * 8;
  bf16x8 qf[4];
#pragma unroll
  for (int kc = 0; kc < 4; ++kc) qf[kc] = *(const bf16x8*)(qp + kc * 16);

  float l4[4] = {0.f, 0.f, 0.f, 0.f};
  f32x16 o0, o1;
#pragma unroll
  for (int r = 0; r < 16; ++r) { o0[r] = 0.f; o1[r] = 0.f; }

  // prologue: stage 128-key tile 0 (both 64-key halves) into buf 0
#pragma unroll
  for (int s = 0; s < 2; ++s) {
    gld16(kbase + (size_t)(s * 64 + row8) * RS, (char*)smem[0][0][s] + tid * 16);
    gld16(vbase + (size_t)row8 * 2048 + s * 64, (char*)smem[1][0][s] + tid * 16);
  }
  __syncthreads();

  for (int it = 0; it < nit; ++it) {
    const int cur = it & 1;
    if (it < qb) {  // guarded prefetch of tile it+1
      const int kb2 = (it + 1) * 128;
#pragma unroll
      for (int s = 0; s < 2; ++s) {
        gld16(kbase + (size_t)(kb2 + s * 64 + row8) * RS,
              (char*)smem[0][cur ^ 1][s] + tid * 16);
        gld16(vbase + (size_t)row8 * 2048 + kb2 + s * 64,
              (char*)smem[1][cur ^ 1][s] + tid * 16);
      }
    }

    const int kt = 2 * it + kh;
    if (kt <= ktmax) {  // wave-uniform skip of fully-masked subtiles
      const __bf16* Kc = smem[0][cur][kh];
      const __bf16* Vc = smem[1][cur][kh];

      // S^T = K Q^T : c[kb][r] = S^T[key=kb*32+(r&3)+8*(r>>2)+4*hi][q=l32]
      f32x16 c0, c1;
#pragma unroll
      for (int r = 0; r < 16; ++r) { c0[r] = 0.f; c1[r] = 0.f; }
      __builtin_amdgcn_s_setprio(1);
#pragma unroll
      for (int kc = 0; kc < 4; ++kc) {
        const int sw = ((kc * 2 + hi) ^ xr) << 3;
        bf16x8 kf0 = *(const bf16x8*)&Kc[l32 * 64 + sw];
        bf16x8 kf1 = *(const bf16x8*)&Kc[(32 + l32) * 64 + sw];
        c0 = MFMA32(kf0, qf[kc], c0);
        c1 = MFMA32(kf1, qf[kc], c1);
      }
      __builtin_amdgcn_s_setprio(0);

      // causal mask only on the diagonal subtile
      if (kt == ktmax) {
        const int qloc = qh * 32 + l32 - (kt - 2 * qb) * 64;
#pragma unroll
        for (int r = 0; r < 16; ++r) {
          const int kl = (r & 3) + 8 * (r >> 2) + 4 * hi;
          if (kl > qloc) c0[r] = NEG_INF;
          if (32 + kl > qloc) c1[r] = NEG_INF;
        }
      }

      // interleaved softmax/PV ladder: SM(kb0) -> PV(kc0,1) -> SM(kb1) -> PV(kc2,3)
      bf16x8 pb[4];
#pragma unroll
      for (int kb = 0; kb < 2; ++kb) {
        float pv[16];
#pragma unroll
        for (int r = 0; r < 16; ++r) {
          const float sv = (kb ? c1[r] : c0[r]);
          pv[r] = __builtin_amdgcn_exp2f(sv * SCL);
          l4[r & 3] += pv[r];
        }
        u32 a0, a1, b0, b1;
        CVTPK(a0, pv[0], pv[1]);   CVTPK(a1, pv[2], pv[3]);
        CVTPK(b0, pv[4], pv[5]);   CVTPK(b1, pv[6], pv[7]);
        SWAP32(a0, b0); SWAP32(a1, b1);
        pb[kb * 2 + 0] = mk8(a0, a1, b0, b1);
        CVTPK(a0, pv[8], pv[9]);   CVTPK(a1, pv[10], pv[11]);
        CVTPK(b0, pv[12], pv[13]); CVTPK(b1, pv[14], pv[15]);
        SWAP32(a0, b0); SWAP32(a1, b1);
        pb[kb * 2 + 1] = mk8(a0, a1, b0, b1);

        // PV for this kb's two key-chunks (kc = kb*2, kb*2+1)
        __builtin_amdgcn_s_setprio(1);
#pragma unroll
        for (int kq = 0; kq < 2; ++kq) {
          const int kc = kb * 2 + kq;
          const int sw = ((kc * 2 + hi) ^ xr) << 3;
          bf16x8 vf0 = *(const bf16x8*)&Vc[l32 * 64 + sw];
          bf16x8 vf1 = *(const bf16x8*)&Vc[(32 + l32) * 64 + sw];
          o0 = MFMA32(vf0, pb[kc], o0);
          o1 = MFMA32(vf1, pb[kc], o1);
        }
        __builtin_amdgcn_s_setprio(0);
      }
    }
    __syncthreads();  // drains this iter's DMA; next tile ready for all waves
  }

  // l: lane owns 32 of each 64-key subtile; partner (lane^32) owns the rest
  float lred = (l4[0] + l4[1]) + (l4[2] + l4[3]);
  lred += __shfl_xor(lred, 32);

  // cross-wave (kh) combine via LDS scratch (aliases K/V buffers; loop done)
  float* sc = (float*)smem;  // o: [qh][2048 floats] in first 32 KB; l after
  if (kh == 1) {
    float* ob = sc + qh * 2048;
#pragma unroll
    for (int r = 0; r < 16; ++r) {
      ob[r * 64 + lane] = o0[r];
      ob[1024 + r * 64 + lane] = o1[r];
    }
    if (lane < 32) sc[8192 + qh * 32 + lane] = lred;
  }
  __syncthreads();
  if (kh == 0) {
    const float* ob = sc + qh * 2048;
    lred += sc[8192 + qh * 32 + l32];
    const float inv = 1.f / lred;
    const int orow = b * 2048 + qb * 128 + qh * 32 + l32;
    __bf16* yb = y + (size_t)orow * 1024 + h * 64 + hi * 4;
#pragma unroll
    for (int db = 0; db < 2; ++db) {
#pragma unroll
      for (int g = 0; g < 4; ++g) {
        bf16x4 w;
#pragma unroll
        for (int j = 0; j < 4; ++j) {
          const float v = (db ? o1[g * 4 + j] : o0[g * 4 + j]) +
                          ob[db * 1024 + (g * 4 + j) * 64 + lane];
          w[j] = (__bf16)(v * inv);
        }
        *(bf16x4*)&yb[db * 32 + g * 8] = w;
      }
    }
  }
}

// ---------------------------------------------------------------------------
extern "C" void kernel_launch(void* const* d_in, const int* in_sizes, int n_in,
                              void* d_out, int out_size, void* d_ws, size_t ws_size,
                              hipStream_t stream) {
  (void)in_sizes; (void)n_in; (void)out_size; (void)ws_size;
  const float* x      = (const float*)d_in[0];  // [2,2048,1024] fp32
  const float* w_attn = (const float*)d_in[1];  // [1024,3072]
  const float* b_attn = (const float*)d_in[2];  // [3072]
  const float* w_proj = (const float*)d_in[3];  // [1024,1024]
  const float* b_proj = (const float*)d_in[4];  // [1024]
  float* out = (float*)d_out;                   // [2,2048,1024] fp32

  __bf16* wt_attn = (__bf16*)d_ws;                       // [3072][1024]
  __bf16* wt_proj = wt_attn + (size_t)3072 * 1024;       // [1024][1024]
  __bf16* qkv     = wt_proj + (size_t)1024 * 1024;       // [4096][3072]
  __bf16* ybuf    = qkv + (size_t)4096 * 3072;           // [4096][1024]
  __bf16* vtbuf   = ybuf + (size_t)4096 * 1024;          // [32*64][2048]

  // x -> bf16, staged in ybuf (attention overwrites it later; same stream)
  cast_f32_bf16<<<4096 * 1024 / 2048, 256, 0, stream>>>(x, ybuf, 4096 * 1024);

  transpose_f32_bf16<<<dim3(3072 / 32, 1024 / 32), 256, 0, stream>>>(w_attn, wt_attn, 1024, 3072);
  transpose_f32_bf16<<<dim3(1024 / 32, 1024 / 32), 256, 0, stream>>>(w_proj, wt_proj, 1024, 1024);

  // qkv = x @ w_attn + b_attn; V columns written transposed into vtbuf
  // (8-phase 256x192 tile; grid 16x16 = 256 blocks = 1/CU)
  gemm_qkv_8ph<<<dim3(3072 / 192, 4096 / 256), 512, 0, stream>>>(
      ybuf, wt_attn, b_attn, qkv, vtbuf);

  // y = causal_attention(qkv, vt), overwrites ybuf
  // (512 blocks of 512 threads = 16 waves/CU; qb mapped big-first + CU-paired)
  attn_causal<<<dim3(32, 16), 512, 0, stream>>>(qkv, vtbuf, ybuf);

  // out = y @ w_proj + b_proj   (512 blocks, BM=64 for occupancy)
  gemm_bt_bias<64, float><<<dim3(1024 / BN, 4096 / 64), 256, 0, stream>>>(
      ybuf, wt_proj, b_proj, out, 4096, 1024, 1024);
}